// Round 11
// baseline (147.170 us; speedup 1.0000x reference)
//
#include <hip/hip_runtime.h>
#include <hip/hip_bf16.h>
#include <math.h>

#define Bn 4
#define Nn 512
#define Dn 128
#define Hn 64
#define TT 4096                  // table resolution (nearest-neighbor lookup)
#define EPB 8
#define K0B ((TT + 1 + EPB - 1) / EPB)

__device__ __forceinline__ float silu_f(float x) {
    return x * (1.0f / (1.0f + __expf(-x)));
}

// ---------------------------------------------------------------------------
// k0: tabulate radial MLP G(x): scalar -> R^128 at x = e/TT (R7-R10 verified).
// ---------------------------------------------------------------------------
struct K0S {
    float rW2s[Hn][Hn];
    float rW3s[Hn][Dn];
    float rW1s[Hn], rb1s[Hn], rg1s[Hn], rb2s[Hn], rg2s[Hn];
    float rb3s[Dn];
    float h1buf[4][Hn];
    float h2buf[4][Hn];
};

__global__ __launch_bounds__(256)
void k0_build_table(const float* __restrict__ rW1, const float* __restrict__ rb1,
                    const float* __restrict__ rg1,
                    const float* __restrict__ rW2, const float* __restrict__ rb2,
                    const float* __restrict__ rg2,
                    const float* __restrict__ rW3, const float* __restrict__ rb3,
                    __hip_bfloat16* __restrict__ table)
{
    __shared__ K0S sm;
    const int t   = threadIdx.x;
    const int k   = t & 63;
    const int wv  = t >> 6;
    const int blk = blockIdx.x;

    #pragma unroll
    for (int idx = t; idx < Hn * Hn; idx += 256)
        sm.rW2s[idx >> 6][idx & 63] = rW2[idx];
    #pragma unroll
    for (int idx = t; idx < Hn * Dn; idx += 256)
        sm.rW3s[idx >> 7][idx & 127] = rW3[idx];
    if (t < Hn) {
        sm.rW1s[t] = rW1[t];
        sm.rb1s[t] = rb1[t];
        sm.rg1s[t] = rg1[t];
        sm.rb2s[t] = rb2[t];
        sm.rg2s[t] = rg2[t];
    }
    if (t < Dn) sm.rb3s[t] = rb3[t];
    __syncthreads();

    for (int r = 0; r < 2; ++r) {
        const int e = blk * EPB + r * 4 + wv;
        const float x = (float)e * (1.0f / (float)TT);

        float h = silu_f(x * sm.rW1s[k] + sm.rb1s[k]);
        float s1 = h, s2 = h * h;
        #pragma unroll
        for (int m = 1; m < 64; m <<= 1) { s1 += __shfl_xor(s1, m); s2 += __shfl_xor(s2, m); }
        float mean = s1 * (1.0f / 64.0f);
        float var  = s2 * (1.0f / 64.0f) - mean * mean;
        float rs   = rsqrtf(var + 1e-5f);
        sm.h1buf[wv][k] = (h - mean) * rs * sm.rg1s[k];
        __syncthreads();

        float p = 0.f;
        #pragma unroll 8
        for (int kk = 0; kk < Hn; ++kk) p += sm.h1buf[wv][kk] * sm.rW2s[kk][k];
        float h2 = silu_f(p + sm.rb2s[k]);
        s1 = h2; s2 = h2 * h2;
        #pragma unroll
        for (int m = 1; m < 64; m <<= 1) { s1 += __shfl_xor(s1, m); s2 += __shfl_xor(s2, m); }
        mean = s1 * (1.0f / 64.0f);
        var  = s2 * (1.0f / 64.0f) - mean * mean;
        rs   = rsqrtf(var + 1e-5f);
        sm.h2buf[wv][k] = (h2 - mean) * rs * sm.rg2s[k];
        __syncthreads();

        #pragma unroll
        for (int dd = 0; dd < 2; ++dd) {
            const int d = dd * 64 + k;
            float f = sm.rb3s[d];
            #pragma unroll 8
            for (int kk = 0; kk < Hn; ++kk) f += sm.h2buf[wv][kk] * sm.rW3s[kk][d];
            if (e <= TT) table[e * Dn + d] = __float2bfloat16(f);
        }
        __syncthreads();
    }
}

// ---------------------------------------------------------------------------
// k1: fused contraction + node MLP.  Block = (b, 2 rows); 1024 blocks.
//   Wave wv owns (row = wv>>1, j-half = wv&1): wave-level ballot compaction
//   into a PRIVATE LDS list, then a barrier-free contraction over its list
//   (lane owns d0 = 2*lane).  Only 2 block barriers before the epilogue;
//   ntab staging amortized over 2 rows.  Epilogue = R10-verified og/ch
//   float4 GEMVs, looped over the 2 rows.  LDS unioned to 39.9KB (4 blk/CU).
// ---------------------------------------------------------------------------
struct K1S {
    __hip_bfloat162 ntabS[100 * 64];       // 25.6 KB
    union {
        float2 ent[4][256];                // wave-private entry lists (8 KB)
        struct {
            float xs[256];
            float x2[128];
            float r1[2], r2[2];
        } epi;                             // epilogue scratch (overlays ent)
    } u;
    float accs[4][64][2];                  // 2 KB
    float pp[8][128];                      // 4 KB GEMV partials
};

__global__ __launch_bounds__(256)
void k1_fused(const int* __restrict__ atoms, const float* __restrict__ rel,
              const int* __restrict__ adj, const int* __restrict__ mask,
              const float* __restrict__ soft, const float* __restrict__ ntab,
              const __hip_bfloat16* __restrict__ table,
              const float* __restrict__ atom_tab,
              const float* __restrict__ nW1, const float* __restrict__ nb1,
              const float* __restrict__ ng,
              const float* __restrict__ nW2, const float* __restrict__ nb2,
              float* __restrict__ out)
{
    __shared__ K1S sm;
    const int t    = threadIdx.x;
    const int lane = t & 63;
    const int wv   = t >> 6;
    const int beta = blockIdx.x;        // b * 256 + row-pair
    const int b    = beta >> 8;
    const int ip   = beta & 255;

    // ---- stage ntab -> LDS bf16 (coalesced float2 reads, once per block) ----
    for (int idx = t; idx < 100 * 64; idx += 256) {
        const float2 fv = ((const float2*)ntab)[idx];
        sm.ntabS[idx] = __hip_bfloat162(__float2bfloat16(fv.x), __float2bfloat16(fv.y));
    }

    // ---- wave-private ballot compaction (no cross-wave exchange) ----
    const int rwv = wv >> 1;            // which of the 2 rows
    const int hf  = wv & 1;             // j-half
    const int ig  = ip * 2 + rwv;       // row index i within batch
    const int rowbase = (b * Nn + ig) * Nn;
    const unsigned long long below = (1ull << lane) - 1ull;

    int cnt = 0;
    #pragma unroll
    for (int c = 0; c < 4; ++c) {
        const int j = hf * 256 + c * 64 + lane;
        const float dist = rel[rowbase + j];
        const int   adjv = adj[rowbase + j];
        const int   mk   = mask[b * Nn + j];
        const float w = (adjv != 0 && mk != 0 && j != ig) ? soft[rowbase + j] : 0.0f;
        int e = (int)(dist * (float)TT + 0.5f);
        e = min(max(e, 0), TT);
        const bool act = (w != 0.0f);
        const unsigned long long bm = __ballot(act);
        const int pre = __popcll(bm & below);
        if (act) sm.u.ent[wv][cnt + pre] =
            make_float2(w, __int_as_float(e | (atoms[b * Nn + j] << 16)));
        cnt += (int)__popcll(bm);
    }
    const int padded = (cnt + 7) & ~7;          // <= 256
    if (lane < padded - cnt)
        sm.u.ent[wv][cnt + lane] = make_float2(0.0f, __int_as_float(0));
    __syncthreads();    // ntabS + all ent lists visible

    // ---- barrier-free wave-private contraction ----
    const int dd0 = lane * 2;
    float a0 = 0.f, a1 = 0.f;
    #pragma unroll 8
    for (int n = 0; n < padded; ++n) {
        const float2 E  = sm.u.ent[wv][n];      // own list, broadcast
        const float w   = E.x;
        const int  meta = __float_as_int(E.y);
        const int  e    = meta & 0xFFFF;
        const int  at   = meta >> 16;
        const __hip_bfloat162 tv2 = *(const __hip_bfloat162*)&table[e * Dn + dd0];
        const __hip_bfloat162 nv2 = sm.ntabS[at * 64 + lane];
        const float2 tv = __bfloat1622float2(tv2);
        const float2 nv = __bfloat1622float2(nv2);
        a0 += (w * nv.x) * tv.x;
        a1 += (w * nv.y) * tv.y;
    }
    sm.accs[wv][lane][0] = a0;
    sm.accs[wv][lane][1] = a1;
    __syncthreads();    // ent lists dead from here (union reuse OK)

    // ---- epilogue: R10-verified og/ch GEMVs, looped over the 2 rows ----
    const int og = t & 31;       // outputs 4*og .. 4*og+3
    const int ch = t >> 5;       // c-chunk 0..7

    for (int r = 0; r < 2; ++r) {
        const int bi_r = b * Nn + ip * 2 + r;

        if (t < Dn) {
            const float nf = sm.accs[2 * r][t >> 1][t & 1]
                           + sm.accs[2 * r + 1][t >> 1][t & 1];
            sm.u.epi.xs[t]       = atom_tab[atoms[bi_r] * Dn + t];
            sm.u.epi.xs[128 + t] = nf;
        }
        __syncthreads();

        // GEMV1: c in [ch*32, ch*32+32)
        {
            const int c0 = ch * 32;
            float q0 = 0.f, q1 = 0.f, q2 = 0.f, q3 = 0.f;
            #pragma unroll 8
            for (int c = 0; c < 32; ++c) {
                const float  xv  = sm.u.epi.xs[c0 + c];
                const float4 wv4 = *(const float4*)&nW1[(c0 + c) * Dn + og * 4];
                q0 += xv * wv4.x; q1 += xv * wv4.y; q2 += xv * wv4.z; q3 += xv * wv4.w;
            }
            *(float4*)&sm.pp[ch][og * 4] = make_float4(q0, q1, q2, q3);
        }
        __syncthreads();

        float s = 0.f;
        if (t < Dn) {
            s = nb1[t];
            #pragma unroll
            for (int cc = 0; cc < 8; ++cc) s += sm.pp[cc][t];
            float a1r = s, a2r = s * s;
            #pragma unroll
            for (int off = 32; off > 0; off >>= 1) {
                a1r += __shfl_down(a1r, off);
                a2r += __shfl_down(a2r, off);
            }
            if ((t & 63) == 0) { sm.u.epi.r1[t >> 6] = a1r; sm.u.epi.r2[t >> 6] = a2r; }
        }
        __syncthreads();

        if (t < Dn) {
            const float S1 = sm.u.epi.r1[0] + sm.u.epi.r1[1];
            const float S2 = sm.u.epi.r2[0] + sm.u.epi.r2[1];
            const float m  = S1 * (1.0f / 128.0f);
            const float vr = S2 * (1.0f / 128.0f) - m * m;
            const float rs = rsqrtf(vr + 1e-5f);
            sm.u.epi.x2[t] = silu_f((s - m) * rs * ng[t]);   // LN first, THEN silu
        }
        __syncthreads();

        // GEMV2: c in [ch*16, ch*16+16)
        {
            const int c0 = ch * 16;
            float q0 = 0.f, q1 = 0.f, q2 = 0.f, q3 = 0.f;
            #pragma unroll
            for (int c = 0; c < 16; ++c) {
                const float  xv  = sm.u.epi.x2[c0 + c];
                const float4 wv4 = *(const float4*)&nW2[(c0 + c) * Dn + og * 4];
                q0 += xv * wv4.x; q1 += xv * wv4.y; q2 += xv * wv4.z; q3 += xv * wv4.w;
            }
            *(float4*)&sm.pp[ch][og * 4] = make_float4(q0, q1, q2, q3);
        }
        __syncthreads();

        if (t < Dn) {
            float rr = nb2[t];
            #pragma unroll
            for (int cc = 0; cc < 8; ++cc) rr += sm.pp[cc][t];
            out[bi_r * Dn + t] = rr;
        }
        __syncthreads();    // protect xs/pp for next row
    }
}

// ---------------------------------------------------------------------------
extern "C" void kernel_launch(void* const* d_in, const int* in_sizes, int n_in,
                              void* d_out, int out_size, void* d_ws, size_t ws_size,
                              hipStream_t stream)
{
    (void)in_sizes; (void)n_in; (void)out_size; (void)ws_size;

    const int*   atoms = (const int*)d_in[0];
    const float* rel   = (const float*)d_in[1];
    const int*   adj   = (const int*)d_in[2];
    const int*   mask  = (const int*)d_in[3];
    const float* soft  = (const float*)d_in[4];
    const float* atab  = (const float*)d_in[5];
    const float* ntab  = (const float*)d_in[6];
    const float* rW1   = (const float*)d_in[7];
    const float* rb1   = (const float*)d_in[8];
    const float* rg1   = (const float*)d_in[9];
    const float* rW2   = (const float*)d_in[10];
    const float* rb2   = (const float*)d_in[11];
    const float* rg2   = (const float*)d_in[12];
    const float* rW3   = (const float*)d_in[13];
    const float* rb3   = (const float*)d_in[14];
    const float* nW1   = (const float*)d_in[15];
    const float* nb1   = (const float*)d_in[16];
    const float* ng    = (const float*)d_in[17];
    const float* nW2   = (const float*)d_in[18];
    const float* nb2   = (const float*)d_in[19];

    __hip_bfloat16* table = (__hip_bfloat16*)d_ws;   // (TT+1) x 128 bf16 ~ 1 MB
    float* out = (float*)d_out;

    hipLaunchKernelGGL(k0_build_table, dim3(K0B), dim3(256), 0, stream,
                       rW1, rb1, rg1, rW2, rb2, rg2, rW3, rb3, table);
    hipLaunchKernelGGL(k1_fused, dim3(Bn * Nn / 2), dim3(256), 0, stream,
                       atoms, rel, adj, mask, soft, ntab, table,
                       atab, nW1, nb1, ng, nW2, nb2, out);
}

// Round 12
// 140.148 us; speedup vs baseline: 1.0501x; 1.0501x over previous
//
#include <hip/hip_runtime.h>
#include <hip/hip_bf16.h>
#include <math.h>

#define Bn 4
#define Nn 512
#define Dn 128
#define Hn 64
#define TT 4096                  // table resolution (nearest-neighbor lookup)
#define EPB 8
#define K0B ((TT + 1 + EPB - 1) / EPB)
#define NF_OFF 1048832           // bytes: (TT+1)*128*2 table, 16B-aligned

__device__ __forceinline__ float silu_f(float x) {
    return x * (1.0f / (1.0f + __expf(-x)));
}

// ---------------------------------------------------------------------------
// k0: tabulate radial MLP G(x): scalar -> R^128 at x = e/TT (R7-R11 verified).
// ---------------------------------------------------------------------------
struct K0S {
    float rW2s[Hn][Hn];
    float rW3s[Hn][Dn];
    float rW1s[Hn], rb1s[Hn], rg1s[Hn], rb2s[Hn], rg2s[Hn];
    float rb3s[Dn];
    float h1buf[4][Hn];
    float h2buf[4][Hn];
};

__global__ __launch_bounds__(256)
void k0_build_table(const float* __restrict__ rW1, const float* __restrict__ rb1,
                    const float* __restrict__ rg1,
                    const float* __restrict__ rW2, const float* __restrict__ rb2,
                    const float* __restrict__ rg2,
                    const float* __restrict__ rW3, const float* __restrict__ rb3,
                    __hip_bfloat16* __restrict__ table)
{
    __shared__ K0S sm;
    const int t   = threadIdx.x;
    const int k   = t & 63;
    const int wv  = t >> 6;
    const int blk = blockIdx.x;

    #pragma unroll
    for (int idx = t; idx < Hn * Hn; idx += 256)
        sm.rW2s[idx >> 6][idx & 63] = rW2[idx];
    #pragma unroll
    for (int idx = t; idx < Hn * Dn; idx += 256)
        sm.rW3s[idx >> 7][idx & 127] = rW3[idx];
    if (t < Hn) {
        sm.rW1s[t] = rW1[t];
        sm.rb1s[t] = rb1[t];
        sm.rg1s[t] = rg1[t];
        sm.rb2s[t] = rb2[t];
        sm.rg2s[t] = rg2[t];
    }
    if (t < Dn) sm.rb3s[t] = rb3[t];
    __syncthreads();

    for (int r = 0; r < 2; ++r) {
        const int e = blk * EPB + r * 4 + wv;
        const float x = (float)e * (1.0f / (float)TT);

        float h = silu_f(x * sm.rW1s[k] + sm.rb1s[k]);
        float s1 = h, s2 = h * h;
        #pragma unroll
        for (int m = 1; m < 64; m <<= 1) { s1 += __shfl_xor(s1, m); s2 += __shfl_xor(s2, m); }
        float mean = s1 * (1.0f / 64.0f);
        float var  = s2 * (1.0f / 64.0f) - mean * mean;
        float rs   = rsqrtf(var + 1e-5f);
        sm.h1buf[wv][k] = (h - mean) * rs * sm.rg1s[k];
        __syncthreads();

        float p = 0.f;
        #pragma unroll 8
        for (int kk = 0; kk < Hn; ++kk) p += sm.h1buf[wv][kk] * sm.rW2s[kk][k];
        float h2 = silu_f(p + sm.rb2s[k]);
        s1 = h2; s2 = h2 * h2;
        #pragma unroll
        for (int m = 1; m < 64; m <<= 1) { s1 += __shfl_xor(s1, m); s2 += __shfl_xor(s2, m); }
        mean = s1 * (1.0f / 64.0f);
        var  = s2 * (1.0f / 64.0f) - mean * mean;
        rs   = rsqrtf(var + 1e-5f);
        sm.h2buf[wv][k] = (h2 - mean) * rs * sm.rg2s[k];
        __syncthreads();

        #pragma unroll
        for (int dd = 0; dd < 2; ++dd) {
            const int d = dd * 64 + k;
            float f = sm.rb3s[d];
            #pragma unroll 8
            for (int kk = 0; kk < Hn; ++kk) f += sm.h2buf[wv][kk] * sm.rW3s[kk][d];
            if (e <= TT) table[e * Dn + d] = __float2bfloat16(f);
        }
        __syncthreads();
    }
}

// ---------------------------------------------------------------------------
// k1: contraction only -> nf.  Block = (b, 2 rows); 1024 blocks.
//   Wave wv = (row rwv = wv>>1, j-half hf = wv&1); wave-level ballot into a
//   private LDS list (R11-verified).  Contraction: sub-half s = lane>>5
//   strides entries 2-way; lane covers 4 d's (dwordx2 table load + b64 LDS
//   ntab read) -> ~2/3 the VALU inst of R11.  No node-MLP epilogue (moved
//   to row-tiled k2 to amortize the 192KB/row weight streaming).
// ---------------------------------------------------------------------------
struct K1S {
    __hip_bfloat162 ntabS[100 * 64];       // 25.6 KB
    float2 ent[4][256];                    // wave-private entry lists (8 KB)
    float  accs[4][2][32][4];              // [wv][s][dl][k] -> [wv][s] d-major (4 KB)
};

__global__ __launch_bounds__(256)
void k1_contract(const int* __restrict__ atoms, const float* __restrict__ rel,
                 const int* __restrict__ adj, const int* __restrict__ mask,
                 const float* __restrict__ soft, const float* __restrict__ ntab,
                 const __hip_bfloat16* __restrict__ table,
                 float* __restrict__ nf)
{
    __shared__ K1S sm;
    const int t    = threadIdx.x;
    const int lane = t & 63;
    const int wv   = t >> 6;
    const int beta = blockIdx.x;        // b * 256 + row-pair
    const int b    = beta >> 8;
    const int ip   = beta & 255;

    // ---- stage ntab -> LDS bf16 (coalesced float2 reads, once per block) ----
    for (int idx = t; idx < 100 * 64; idx += 256) {
        const float2 fv = ((const float2*)ntab)[idx];
        sm.ntabS[idx] = __hip_bfloat162(__float2bfloat16(fv.x), __float2bfloat16(fv.y));
    }

    // ---- wave-private ballot compaction (R11-verified) ----
    const int rwv = wv >> 1;            // which of the 2 rows
    const int hf  = wv & 1;             // j-half
    const int ig  = ip * 2 + rwv;       // row index i within batch
    const int rowbase = (b * Nn + ig) * Nn;
    const unsigned long long below = (1ull << lane) - 1ull;

    int cnt = 0;
    #pragma unroll
    for (int c = 0; c < 4; ++c) {
        const int j = hf * 256 + c * 64 + lane;
        const float dist = rel[rowbase + j];
        const int   adjv = adj[rowbase + j];
        const int   mk   = mask[b * Nn + j];
        const float w = (adjv != 0 && mk != 0 && j != ig) ? soft[rowbase + j] : 0.0f;
        int e = (int)(dist * (float)TT + 0.5f);
        e = min(max(e, 0), TT);
        const bool act = (w != 0.0f);
        const unsigned long long bm = __ballot(act);
        const int pre = __popcll(bm & below);
        if (act) sm.ent[wv][cnt + pre] =
            make_float2(w, __int_as_float(e | (atoms[b * Nn + j] << 16)));
        cnt += (int)__popcll(bm);
    }
    const int padded = (cnt + 7) & ~7;          // multiple of 8 (even per s)
    if (lane < padded - cnt)
        sm.ent[wv][cnt + lane] = make_float2(0.0f, __int_as_float(0));
    __syncthreads();

    // ---- contraction: s strides entries, lane covers 4 d's ----
    const int s  = lane >> 5;
    const int dl = lane & 31;
    const int d0 = dl * 4;
    float a0 = 0.f, a1 = 0.f, a2 = 0.f, a3 = 0.f;
    #pragma unroll 8
    for (int n = s; n < padded; n += 2) {
        const float2 E  = sm.ent[wv][n];         // b64, 2-address broadcast
        const float w   = E.x;
        const int  meta = __float_as_int(E.y);
        const int  e    = meta & 0xFFFF;
        const int  at   = meta >> 16;
        const __hip_bfloat162* tp = (const __hip_bfloat162*)&table[e * Dn + d0];
        const __hip_bfloat162 tva = tp[0], tvb = tp[1];          // dwordx2
        const __hip_bfloat162 nva = sm.ntabS[at * 64 + dl * 2];  // b64 pair
        const __hip_bfloat162 nvb = sm.ntabS[at * 64 + dl * 2 + 1];
        const float2 ta = __bfloat1622float2(tva);
        const float2 tb = __bfloat1622float2(tvb);
        const float2 na = __bfloat1622float2(nva);
        const float2 nb = __bfloat1622float2(nvb);
        a0 += (w * na.x) * ta.x;
        a1 += (w * na.y) * ta.y;
        a2 += (w * nb.x) * tb.x;
        a3 += (w * nb.y) * tb.y;
    }
    *(float4*)&sm.accs[wv][s][dl][0] = make_float4(a0, a1, a2, a3);
    __syncthreads();

    // ---- reduce 4 partials per (row, d), write nf ----
    if (t < Dn) {
        const float* base0 = &sm.accs[0][0][0][0];   // [wv][s] planes of 128 d
        #pragma unroll
        for (int r = 0; r < 2; ++r) {
            float v = 0.f;
            #pragma unroll
            for (int hh = 0; hh < 2; ++hh)
                #pragma unroll
                for (int ss = 0; ss < 2; ++ss)
                    v += base0[((2 * r + hh) * 2 + ss) * 128 + t];
            nf[(b * Nn + ip * 2 + r) * Dn + t] = v;
        }
    }
}

// ---------------------------------------------------------------------------
// k2: node MLP, 4-row tiled.  512 blocks x 256 threads; weights loaded once
// per (c, og) and reused across 4 rows (16 FMAs per float4 load).
//   og = t&31 owns outputs 4*og..4*og+3; ch = t>>5 owns a c-chunk.
// ---------------------------------------------------------------------------
struct K2S {
    float xs[4][256];        // 4 KB  input rows [emb | nf]
    float x2[4][128];        // 2 KB  post-LN/silu
    float pp[8][4][128];     // 16 KB GEMV partials [ch][row][out]
    float sarr[4][128];      // 2 KB  pre-LN sums
    float st1[4], st2[4];    // LN stats per row
};

__global__ __launch_bounds__(256)
void k2_node_mlp(const int* __restrict__ atoms,
                 const float* __restrict__ atom_tab,
                 const float* __restrict__ nf,
                 const float* __restrict__ nW1, const float* __restrict__ nb1,
                 const float* __restrict__ ng,
                 const float* __restrict__ nW2, const float* __restrict__ nb2,
                 float* __restrict__ out)
{
    __shared__ K2S sm;
    const int t    = threadIdx.x;
    const int lane = t & 63;
    const int wv   = t >> 6;
    const int bi0  = blockIdx.x * 4;
    const int og   = t & 31;
    const int ch   = t >> 5;

    // ---- stage xs = [embeds | nf] for 4 rows ----
    #pragma unroll
    for (int idx = t; idx < 4 * 256; idx += 256) {
        const int r = idx >> 8, c = idx & 255;
        sm.xs[r][c] = (c < Dn) ? atom_tab[atoms[bi0 + r] * Dn + c]
                               : nf[(bi0 + r) * Dn + (c - Dn)];
    }
    __syncthreads();

    // ---- GEMV1: c-chunk of 32, weights reused across 4 rows ----
    {
        float acc[4][4];
        #pragma unroll
        for (int r = 0; r < 4; ++r)
            #pragma unroll
            for (int k = 0; k < 4; ++k) acc[r][k] = 0.f;
        const int c0 = ch * 32;
        #pragma unroll 8
        for (int c = 0; c < 32; ++c) {
            const float4 wv4 = *(const float4*)&nW1[(c0 + c) * Dn + og * 4];
            #pragma unroll
            for (int r = 0; r < 4; ++r) {
                const float xv = sm.xs[r][c0 + c];
                acc[r][0] += xv * wv4.x; acc[r][1] += xv * wv4.y;
                acc[r][2] += xv * wv4.z; acc[r][3] += xv * wv4.w;
            }
        }
        #pragma unroll
        for (int r = 0; r < 4; ++r)
            *(float4*)&sm.pp[ch][r][og * 4] =
                make_float4(acc[r][0], acc[r][1], acc[r][2], acc[r][3]);
    }
    __syncthreads();

    // ---- sum partials -> sarr ----
    if (t < Dn) {
        #pragma unroll
        for (int r = 0; r < 4; ++r) {
            float s = nb1[t];
            #pragma unroll
            for (int cc = 0; cc < 8; ++cc) s += sm.pp[cc][r][t];
            sm.sarr[r][t] = s;
        }
    }
    __syncthreads();

    // ---- LN stats: wave wv reduces row wv ----
    {
        const float va = sm.sarr[wv][lane];
        const float vb = sm.sarr[wv][lane + 64];
        float s1 = va + vb, s2 = va * va + vb * vb;
        #pragma unroll
        for (int m = 1; m < 64; m <<= 1) { s1 += __shfl_xor(s1, m); s2 += __shfl_xor(s2, m); }
        if (lane == 0) { sm.st1[wv] = s1; sm.st2[wv] = s2; }
    }
    __syncthreads();

    // ---- x2 = silu(LN(s)*ng) for 4 rows (t covers 2 (r,d) combos) ----
    {
        const int r0 = t >> 7, d = t & 127;
        const float gd = ng[d];
        #pragma unroll
        for (int q = 0; q < 2; ++q) {
            const int r = r0 + 2 * q;
            const float m  = sm.st1[r] * (1.0f / 128.0f);
            const float vr = sm.st2[r] * (1.0f / 128.0f) - m * m;
            const float rs = rsqrtf(vr + 1e-5f);
            sm.x2[r][d] = silu_f((sm.sarr[r][d] - m) * rs * gd);  // LN then silu
        }
    }
    __syncthreads();

    // ---- GEMV2: c-chunk of 16 ----
    {
        float acc[4][4];
        #pragma unroll
        for (int r = 0; r < 4; ++r)
            #pragma unroll
            for (int k = 0; k < 4; ++k) acc[r][k] = 0.f;
        const int c0 = ch * 16;
        #pragma unroll
        for (int c = 0; c < 16; ++c) {
            const float4 wv4 = *(const float4*)&nW2[(c0 + c) * Dn + og * 4];
            #pragma unroll
            for (int r = 0; r < 4; ++r) {
                const float xv = sm.x2[r][c0 + c];
                acc[r][0] += xv * wv4.x; acc[r][1] += xv * wv4.y;
                acc[r][2] += xv * wv4.z; acc[r][3] += xv * wv4.w;
            }
        }
        #pragma unroll
        for (int r = 0; r < 4; ++r)
            *(float4*)&sm.pp[ch][r][og * 4] =
                make_float4(acc[r][0], acc[r][1], acc[r][2], acc[r][3]);
    }
    __syncthreads();

    if (t < Dn) {
        #pragma unroll
        for (int r = 0; r < 4; ++r) {
            float s = nb2[t];
            #pragma unroll
            for (int cc = 0; cc < 8; ++cc) s += sm.pp[cc][r][t];
            out[(bi0 + r) * Dn + t] = s;
        }
    }
}

// ---------------------------------------------------------------------------
extern "C" void kernel_launch(void* const* d_in, const int* in_sizes, int n_in,
                              void* d_out, int out_size, void* d_ws, size_t ws_size,
                              hipStream_t stream)
{
    (void)in_sizes; (void)n_in; (void)out_size; (void)ws_size;

    const int*   atoms = (const int*)d_in[0];
    const float* rel   = (const float*)d_in[1];
    const int*   adj   = (const int*)d_in[2];
    const int*   mask  = (const int*)d_in[3];
    const float* soft  = (const float*)d_in[4];
    const float* atab  = (const float*)d_in[5];
    const float* ntab  = (const float*)d_in[6];
    const float* rW1   = (const float*)d_in[7];
    const float* rb1   = (const float*)d_in[8];
    const float* rg1   = (const float*)d_in[9];
    const float* rW2   = (const float*)d_in[10];
    const float* rb2   = (const float*)d_in[11];
    const float* rg2   = (const float*)d_in[12];
    const float* rW3   = (const float*)d_in[13];
    const float* rb3   = (const float*)d_in[14];
    const float* nW1   = (const float*)d_in[15];
    const float* nb1   = (const float*)d_in[16];
    const float* ng    = (const float*)d_in[17];
    const float* nW2   = (const float*)d_in[18];
    const float* nb2   = (const float*)d_in[19];

    __hip_bfloat16* table = (__hip_bfloat16*)d_ws;            // ~1 MB
    float* nf  = (float*)((char*)d_ws + NF_OFF);              // 1 MB
    float* out = (float*)d_out;

    hipLaunchKernelGGL(k0_build_table, dim3(K0B), dim3(256), 0, stream,
                       rW1, rb1, rg1, rW2, rb2, rg2, rW3, rb3, table);
    hipLaunchKernelGGL(k1_contract, dim3(Bn * Nn / 2), dim3(256), 0, stream,
                       atoms, rel, adj, mask, soft, ntab, table, nf);
    hipLaunchKernelGGL(k2_node_mlp, dim3(Bn * Nn / 4), dim3(256), 0, stream,
                       atoms, atab, nf, nW1, nb1, ng, nW2, nb2, out);
}

// Round 13
// 135.320 us; speedup vs baseline: 1.0876x; 1.0357x over previous
//
#include <hip/hip_runtime.h>
#include <hip/hip_bf16.h>
#include <math.h>

#define Bn 4
#define Nn 512
#define Dn 128
#define Hn 64
#define TT 4096                  // table resolution (nearest-neighbor lookup)
#define EPB 8
#define K0B ((TT + 1 + EPB - 1) / EPB)

__device__ __forceinline__ float silu_f(float x) {
    return x * (1.0f / (1.0f + __expf(-x)));
}

// ---------------------------------------------------------------------------
// k0: tabulate radial MLP G(x): scalar -> R^128 at x = e/TT (R7-R12 verified).
// ---------------------------------------------------------------------------
struct K0S {
    float rW2s[Hn][Hn];
    float rW3s[Hn][Dn];
    float rW1s[Hn], rb1s[Hn], rg1s[Hn], rb2s[Hn], rg2s[Hn];
    float rb3s[Dn];
    float h1buf[4][Hn];
    float h2buf[4][Hn];
};

__global__ __launch_bounds__(256)
void k0_build_table(const float* __restrict__ rW1, const float* __restrict__ rb1,
                    const float* __restrict__ rg1,
                    const float* __restrict__ rW2, const float* __restrict__ rb2,
                    const float* __restrict__ rg2,
                    const float* __restrict__ rW3, const float* __restrict__ rb3,
                    __hip_bfloat16* __restrict__ table)
{
    __shared__ K0S sm;
    const int t   = threadIdx.x;
    const int k   = t & 63;
    const int wv  = t >> 6;
    const int blk = blockIdx.x;

    #pragma unroll
    for (int idx = t; idx < Hn * Hn; idx += 256)
        sm.rW2s[idx >> 6][idx & 63] = rW2[idx];
    #pragma unroll
    for (int idx = t; idx < Hn * Dn; idx += 256)
        sm.rW3s[idx >> 7][idx & 127] = rW3[idx];
    if (t < Hn) {
        sm.rW1s[t] = rW1[t];
        sm.rb1s[t] = rb1[t];
        sm.rg1s[t] = rg1[t];
        sm.rb2s[t] = rb2[t];
        sm.rg2s[t] = rg2[t];
    }
    if (t < Dn) sm.rb3s[t] = rb3[t];
    __syncthreads();

    for (int r = 0; r < 2; ++r) {
        const int e = blk * EPB + r * 4 + wv;
        const float x = (float)e * (1.0f / (float)TT);

        float h = silu_f(x * sm.rW1s[k] + sm.rb1s[k]);
        float s1 = h, s2 = h * h;
        #pragma unroll
        for (int m = 1; m < 64; m <<= 1) { s1 += __shfl_xor(s1, m); s2 += __shfl_xor(s2, m); }
        float mean = s1 * (1.0f / 64.0f);
        float var  = s2 * (1.0f / 64.0f) - mean * mean;
        float rs   = rsqrtf(var + 1e-5f);
        sm.h1buf[wv][k] = (h - mean) * rs * sm.rg1s[k];
        __syncthreads();

        float p = 0.f;
        #pragma unroll 8
        for (int kk = 0; kk < Hn; ++kk) p += sm.h1buf[wv][kk] * sm.rW2s[kk][k];
        float h2 = silu_f(p + sm.rb2s[k]);
        s1 = h2; s2 = h2 * h2;
        #pragma unroll
        for (int m = 1; m < 64; m <<= 1) { s1 += __shfl_xor(s1, m); s2 += __shfl_xor(s2, m); }
        mean = s1 * (1.0f / 64.0f);
        var  = s2 * (1.0f / 64.0f) - mean * mean;
        rs   = rsqrtf(var + 1e-5f);
        sm.h2buf[wv][k] = (h2 - mean) * rs * sm.rg2s[k];
        __syncthreads();

        #pragma unroll
        for (int dd = 0; dd < 2; ++dd) {
            const int d = dd * 64 + k;
            float f = sm.rb3s[d];
            #pragma unroll 8
            for (int kk = 0; kk < Hn; ++kk) f += sm.h2buf[wv][kk] * sm.rW3s[kk][d];
            if (e <= TT) table[e * Dn + d] = __float2bfloat16(f);
        }
        __syncthreads();
    }
}

// ---------------------------------------------------------------------------
// k1: fully fused.  Block = 4 rows (512 blocks); wave = one full row.
//   - ntab staged in LDS bf16 once per 4 rows (R8/R11-verified)
//   - wave-private ballot compaction over 8 chunks (R11/R12-verified)
//   - contraction: s = lane>>5 strides entries 2-way, lane covers 4 d's
//     (dwordx2 table load + 2x b64 LDS ntab) (R12-verified)
//   - epilogue: R12-verified 4-row-tiled node MLP (weights reused across
//     4 rows, 16 FMAs per float4 load) -- nf never leaves LDS.
//   LDS 53.8 KB via union (ent dead before epilogue) -> 2 blocks/CU.
// ---------------------------------------------------------------------------
struct K1S {
    __hip_bfloat162 ntabS[100 * 64];       // 25.6 KB
    union {
        float2 ent[4][512];                // wave-private entry lists (16 KB)
        struct {
            float xs[4][256];              // 4 KB  [emb | nf] per row
            float pp[8][4][128];           // 16 KB GEMV partials [ch][row][out]
            float sarr[4][128];            // 2 KB  pre-LN sums
            float x2[4][128];              // 2 KB  post-LN/silu
            float st1[4], st2[4];          // LN stats
        } epi;                             // 24.2 KB
    } u;
    float accs[4][2][32][4];               // [row][s][dl][k]  4 KB
};

__global__ __launch_bounds__(256)
void k1_fused(const int* __restrict__ atoms, const float* __restrict__ rel,
              const int* __restrict__ adj, const int* __restrict__ mask,
              const float* __restrict__ soft, const float* __restrict__ ntab,
              const __hip_bfloat16* __restrict__ table,
              const float* __restrict__ atom_tab,
              const float* __restrict__ nW1, const float* __restrict__ nb1,
              const float* __restrict__ ng,
              const float* __restrict__ nW2, const float* __restrict__ nb2,
              float* __restrict__ out)
{
    __shared__ K1S sm;
    const int t    = threadIdx.x;
    const int lane = t & 63;
    const int wv   = t >> 6;
    const int bi0  = blockIdx.x * 4;       // first global row of this block
    const int b    = bi0 >> 9;             // batch (4 rows never straddle b)

    // ---- stage ntab -> LDS bf16 (once per 4 rows) ----
    for (int idx = t; idx < 100 * 64; idx += 256) {
        const float2 fv = ((const float2*)ntab)[idx];
        sm.ntabS[idx] = __hip_bfloat162(__float2bfloat16(fv.x), __float2bfloat16(fv.y));
    }

    // ---- wave-private ballot compaction: wave wv owns row bi0+wv ----
    const int ig      = bi0 + wv;          // global row index
    const int iloc    = ig & 511;          // i within batch
    const int rowbase = ig * Nn;
    const unsigned long long below = (1ull << lane) - 1ull;

    int cnt = 0;
    #pragma unroll
    for (int c = 0; c < 8; ++c) {
        const int j = c * 64 + lane;
        const float dist = rel[rowbase + j];
        const int   adjv = adj[rowbase + j];
        const int   mk   = mask[b * Nn + j];
        const float w = (adjv != 0 && mk != 0 && j != iloc) ? soft[rowbase + j] : 0.0f;
        int e = (int)(dist * (float)TT + 0.5f);
        e = min(max(e, 0), TT);
        const bool act = (w != 0.0f);
        const unsigned long long bm = __ballot(act);
        const int pre = __popcll(bm & below);
        if (act) sm.u.ent[wv][cnt + pre] =
            make_float2(w, __int_as_float(e | (atoms[b * Nn + j] << 16)));
        cnt += (int)__popcll(bm);
    }
    const int padded = (cnt + 7) & ~7;
    if (lane < padded - cnt)
        sm.u.ent[wv][cnt + lane] = make_float2(0.0f, __int_as_float(0));
    __syncthreads();    // ntabS + ent visible

    // ---- contraction (R12-verified): s strides entries, lane covers 4 d ----
    const int s  = lane >> 5;
    const int dl = lane & 31;
    const int d0 = dl * 4;
    float a0 = 0.f, a1 = 0.f, a2 = 0.f, a3 = 0.f;
    #pragma unroll 8
    for (int n = s; n < padded; n += 2) {
        const float2 E  = sm.u.ent[wv][n];
        const float w   = E.x;
        const int  meta = __float_as_int(E.y);
        const int  e    = meta & 0xFFFF;
        const int  at   = meta >> 16;
        const __hip_bfloat162* tp = (const __hip_bfloat162*)&table[e * Dn + d0];
        const __hip_bfloat162 tva = tp[0], tvb = tp[1];
        const __hip_bfloat162 nva = sm.ntabS[at * 64 + dl * 2];
        const __hip_bfloat162 nvb = sm.ntabS[at * 64 + dl * 2 + 1];
        const float2 ta = __bfloat1622float2(tva);
        const float2 tb = __bfloat1622float2(tvb);
        const float2 na = __bfloat1622float2(nva);
        const float2 nb = __bfloat1622float2(nvb);
        a0 += (w * na.x) * ta.x;
        a1 += (w * na.y) * ta.y;
        a2 += (w * nb.x) * tb.x;
        a3 += (w * nb.y) * tb.y;
    }
    *(float4*)&sm.accs[wv][s][dl][0] = make_float4(a0, a1, a2, a3);
    __syncthreads();    // ent dead from here (union reuse OK)

    // ---- epilogue: R12-verified 4-row-tiled node MLP ----
    const int og = t & 31;       // outputs 4*og .. 4*og+3
    const int ch = t >> 5;       // c-chunk 0..7

    // stage xs = [embeds | nf] for the 4 rows (nf straight from accs)
    #pragma unroll
    for (int idx = t; idx < 4 * 256; idx += 256) {
        const int r = idx >> 8, c = idx & 255;
        float v;
        if (c < Dn) {
            v = atom_tab[atoms[bi0 + r] * Dn + c];
        } else {
            const int d  = c - Dn;
            v = sm.accs[r][0][d >> 2][d & 3] + sm.accs[r][1][d >> 2][d & 3];
        }
        sm.u.epi.xs[r][c] = v;
    }
    __syncthreads();

    // GEMV1: c-chunk of 32, weights reused across 4 rows
    {
        float acc[4][4];
        #pragma unroll
        for (int r = 0; r < 4; ++r)
            #pragma unroll
            for (int k = 0; k < 4; ++k) acc[r][k] = 0.f;
        const int c0 = ch * 32;
        #pragma unroll 8
        for (int c = 0; c < 32; ++c) {
            const float4 wv4 = *(const float4*)&nW1[(c0 + c) * Dn + og * 4];
            #pragma unroll
            for (int r = 0; r < 4; ++r) {
                const float xv = sm.u.epi.xs[r][c0 + c];
                acc[r][0] += xv * wv4.x; acc[r][1] += xv * wv4.y;
                acc[r][2] += xv * wv4.z; acc[r][3] += xv * wv4.w;
            }
        }
        #pragma unroll
        for (int r = 0; r < 4; ++r)
            *(float4*)&sm.u.epi.pp[ch][r][og * 4] =
                make_float4(acc[r][0], acc[r][1], acc[r][2], acc[r][3]);
    }
    __syncthreads();

    if (t < Dn) {
        #pragma unroll
        for (int r = 0; r < 4; ++r) {
            float sv = nb1[t];
            #pragma unroll
            for (int cc = 0; cc < 8; ++cc) sv += sm.u.epi.pp[cc][r][t];
            sm.u.epi.sarr[r][t] = sv;
        }
    }
    __syncthreads();

    // LN stats: wave wv reduces row wv
    {
        const float va = sm.u.epi.sarr[wv][lane];
        const float vb = sm.u.epi.sarr[wv][lane + 64];
        float s1 = va + vb, s2 = va * va + vb * vb;
        #pragma unroll
        for (int m = 1; m < 64; m <<= 1) { s1 += __shfl_xor(s1, m); s2 += __shfl_xor(s2, m); }
        if (lane == 0) { sm.u.epi.st1[wv] = s1; sm.u.epi.st2[wv] = s2; }
    }
    __syncthreads();

    // x2 = silu(LN(s)*ng)
    {
        const int r0 = t >> 7, d = t & 127;
        const float gd = ng[d];
        #pragma unroll
        for (int q = 0; q < 2; ++q) {
            const int r = r0 + 2 * q;
            const float m  = sm.u.epi.st1[r] * (1.0f / 128.0f);
            const float vr = sm.u.epi.st2[r] * (1.0f / 128.0f) - m * m;
            const float rs = rsqrtf(vr + 1e-5f);
            sm.u.epi.x2[r][d] = silu_f((sm.u.epi.sarr[r][d] - m) * rs * gd);
        }
    }
    __syncthreads();

    // GEMV2: c-chunk of 16
    {
        float acc[4][4];
        #pragma unroll
        for (int r = 0; r < 4; ++r)
            #pragma unroll
            for (int k = 0; k < 4; ++k) acc[r][k] = 0.f;
        const int c0 = ch * 16;
        #pragma unroll
        for (int c = 0; c < 16; ++c) {
            const float4 wv4 = *(const float4*)&nW2[(c0 + c) * Dn + og * 4];
            #pragma unroll
            for (int r = 0; r < 4; ++r) {
                const float xv = sm.u.epi.x2[r][c0 + c];
                acc[r][0] += xv * wv4.x; acc[r][1] += xv * wv4.y;
                acc[r][2] += xv * wv4.z; acc[r][3] += xv * wv4.w;
            }
        }
        #pragma unroll
        for (int r = 0; r < 4; ++r)
            *(float4*)&sm.u.epi.pp[ch][r][og * 4] =
                make_float4(acc[r][0], acc[r][1], acc[r][2], acc[r][3]);
    }
    __syncthreads();

    if (t < Dn) {
        #pragma unroll
        for (int r = 0; r < 4; ++r) {
            float sv = nb2[t];
            #pragma unroll
            for (int cc = 0; cc < 8; ++cc) sv += sm.u.epi.pp[cc][r][t];
            out[(bi0 + r) * Dn + t] = sv;
        }
    }
}

// ---------------------------------------------------------------------------
extern "C" void kernel_launch(void* const* d_in, const int* in_sizes, int n_in,
                              void* d_out, int out_size, void* d_ws, size_t ws_size,
                              hipStream_t stream)
{
    (void)in_sizes; (void)n_in; (void)out_size; (void)ws_size;

    const int*   atoms = (const int*)d_in[0];
    const float* rel   = (const float*)d_in[1];
    const int*   adj   = (const int*)d_in[2];
    const int*   mask  = (const int*)d_in[3];
    const float* soft  = (const float*)d_in[4];
    const float* atab  = (const float*)d_in[5];
    const float* ntab  = (const float*)d_in[6];
    const float* rW1   = (const float*)d_in[7];
    const float* rb1   = (const float*)d_in[8];
    const float* rg1   = (const float*)d_in[9];
    const float* rW2   = (const float*)d_in[10];
    const float* rb2   = (const float*)d_in[11];
    const float* rg2   = (const float*)d_in[12];
    const float* rW3   = (const float*)d_in[13];
    const float* rb3   = (const float*)d_in[14];
    const float* nW1   = (const float*)d_in[15];
    const float* nb1   = (const float*)d_in[16];
    const float* ng    = (const float*)d_in[17];
    const float* nW2   = (const float*)d_in[18];
    const float* nb2   = (const float*)d_in[19];

    __hip_bfloat16* table = (__hip_bfloat16*)d_ws;   // (TT+1) x 128 bf16 ~ 1 MB
    float* out = (float*)d_out;

    hipLaunchKernelGGL(k0_build_table, dim3(K0B), dim3(256), 0, stream,
                       rW1, rb1, rg1, rW2, rb2, rg2, rW3, rb3, table);
    hipLaunchKernelGGL(k1_fused, dim3(Bn * Nn / 4), dim3(256), 0, stream,
                       atoms, rel, adj, mask, soft, ntab, table,
                       atab, nW1, nb1, ng, nW2, nb2, out);
}